// Round 11
// baseline (69.278 us; speedup 1.0000x reference)
//
#include <hip/hip_runtime.h>

// WaveletMixing: out = x + IDWT3(scale(DWT3(x))) along N per (b,d) channel.
// x: (B=8, N=4096, D=768) f32.
// Interior (n in [256,3840)): register-streaming dataflow, 112 samples per
//   thread (32 segments x 3 ch-groups x 8 batch = 768 blocks = 3.0/CU exact).
//   Loads are software-pipelined ONE SUPERSTEP AHEAD: at the top of step k
//   the stream batch (16) and residual batch (16) for step k+1 are issued
//   into ping-pong register arrays; step k computes purely from registers
//   loaded ~2000 cycles earlier -> load latency fully covered.
//   No LDS, no barriers, no cross-lane in the interior path.
// Edge tiles (n<256, n>=3840): round-5 generic LDS path (proven), same
//   dispatch, after the interior blocks.

namespace {

constexpr int NT  = 256;
constexpr int N0  = 4096;
constexpr int DCH = 768;
constexpr int TS  = 112;             // interior samples per thread
constexpr int TE  = 256;             // edge tile size
constexpr int G   = 8;               // edge path: channels per block
constexpr int NDG = DCH / G;         // 96
constexpr int L1v = 2051, L2v = 1029, L3v = 518;

constexpr int NSEG = (N0 - 2 * TE) / TS;  // 32 interior segments
constexpr int NINT = 8 * 3 * NSEG;        // 768 interior blocks

// Edge LDS pool (round-5 layout, proven)
constexpr int SP = 972;
constexpr int OX = 0, OA1 = 356, OD1 = 536, OA2 = 716, OD2 = 804,
              OA3 = 892, OD3 = 932, OREC = 716;

// db4 analysis filters ascending (pywt); HI[k] = (-1)^(k+1)*LO[7-k].
__device__ constexpr float LO[8] = {
  -0.010597401784997278f,  0.032883011666982945f,  0.030841381835986965f,
  -0.18703481171888114f,  -0.02798376941698385f,   0.6308807679295904f,
   0.7148465705525415f,    0.23037781330885523f };
__device__ constexpr float HI[8] = {
  -0.23037781330885523f,   0.7148465705525415f,   -0.6308807679295904f,
  -0.02798376941698385f,   0.18703481171888114f,   0.030841381835986965f,
  -0.032883011666982945f, -0.010597401784997278f };
// Address-ascending copies: F[7-k].
__device__ constexpr float LOF[8] = {
   0.23037781330885523f,   0.7148465705525415f,    0.6308807679295904f,
  -0.02798376941698385f,  -0.18703481171888114f,   0.030841381835986965f,
   0.032883011666982945f, -0.010597401784997278f };
__device__ constexpr float HIF[8] = {
  -0.010597401784997278f, -0.032883011666982945f,  0.030841381835986965f,
   0.18703481171888114f,  -0.02798376941698385f,  -0.6308807679295904f,
   0.7148465705525415f,   -0.23037781330885523f };

__device__ __forceinline__ int refl(int g, int n) {
  g = (g < 0) ? (-g - 1) : g;
  return (g >= n) ? (2 * n - 1 - g) : g;
}

// ---------------- streaming interior ----------------
// Array origins (abs coeff index of element 0 at the superstep with base bk8):
//  xa:  n0 + bk8 - 54        a1a: n0/2 + bk8/2 - 30   d1a: n0/2 + bk8/2 - 45
//  a2a: n0/4 + bk8/4 - 18    d2a: n0/4 + bk8/4 - 21
//  a3a/d3a: n0/8 + bk8/8 - 9 r2a: n0/4 + bk8/4 - 21   r1a: n0/2 + bk8/2 - 45
struct Streams {
  float xa[22];
  float a1a[14], d1a[29];
  float a2a[10], d2a[13];
  float a3a[5],  d3a[5];
  float r2a[7],  r1a[11];
};

// Issue next superstep's 16 stream loads (abs x offsets bk8-48 .. bk8-33).
__device__ __forceinline__ void issue_stream(float (&L)[16],
                                             const float* __restrict__ xrow,
                                             int bk8) {
  const float* __restrict__ p = xrow + (long)(bk8 - 48) * DCH;
#pragma unroll
  for (int i = 0; i < 16; ++i) L[i] = p[(size_t)i * DCH];
}

// Issue next superstep's 16 residual loads (abs x offsets bk8-90 .. bk8-75).
__device__ __forceinline__ void issue_res(float (&R)[16],
                                          const float* __restrict__ xrow,
                                          int bk8) {
  const float* __restrict__ p = xrow + (long)(bk8 - 90) * DCH;
#pragma unroll
  for (int i = 0; i < 16; ++i) R[i] = p[(size_t)i * DCH];
}

// SMODE: 0 = no stores, 1 = HEAD (store u=1, tau>=1), 2 = FULL, 3 = TAIL
// (store u=0 all + u=1 tau=0). Computes from pre-loaded register batches.
template <int SMODE>
__device__ __forceinline__ void compute_step(Streams& S, const float (&L)[16],
                                             const float (&R)[16],
                                             float* __restrict__ orow, int bk8,
                                             float wa, float w0, float w1,
                                             float w2) {
  // merge prefetched stream batch into the ring
#pragma unroll
  for (int i = 0; i < 16; ++i) S.xa[6 + i] = L[i];

#pragma unroll
  for (int u = 0; u < 2; ++u) {
    // L1 analysis: 4 new a1/d1
#pragma unroll
    for (int j = 0; j < 4; ++j) {
      float slo = 0.f, shi = 0.f;
#pragma unroll
      for (int k = 0; k < 8; ++k) {
        const float v = S.xa[8 * u + 2 * j + k];
        slo = fmaf(LOF[k], v, slo);
        shi = fmaf(HIF[k], v, shi);
      }
      S.a1a[6 + 4 * u + j]  = slo;
      S.d1a[21 + 4 * u + j] = w0 * shi;
    }
    // L2 analysis: 2 new a2/d2
#pragma unroll
    for (int i = 0; i < 2; ++i) {
      float slo = 0.f, shi = 0.f;
#pragma unroll
      for (int k = 0; k < 8; ++k) {
        const float v = S.a1a[4 * u + 2 * i + k];
        slo = fmaf(LOF[k], v, slo);
        shi = fmaf(HIF[k], v, shi);
      }
      S.a2a[6 + 2 * u + i] = slo;
      S.d2a[9 + 2 * u + i] = w1 * shi;
    }
    // L3 analysis: 1 new a3/d3 (wa/w2 folded at production)
    {
      float slo = 0.f, shi = 0.f;
#pragma unroll
      for (int k = 0; k < 8; ++k) {
        const float v = S.a2a[2 * u + k];
        slo = fmaf(LOF[k], v, slo);
        shi = fmaf(HIF[k], v, shi);
      }
      S.a3a[3 + u] = wa * slo;
      S.d3a[3 + u] = w2 * shi;
    }
    // synth L3: 2 new r2 (even output = odd taps, odd output = even taps)
    {
      float e = 0.f, o = 0.f;
#pragma unroll
      for (int m = 0; m < 4; ++m) {
        e = fmaf(LO[2 * m + 1], S.a3a[u + m], e);
        e = fmaf(HI[2 * m + 1], S.d3a[u + m], e);
        o = fmaf(LO[2 * m],     S.a3a[u + m], o);
        o = fmaf(HI[2 * m],     S.d3a[u + m], o);
      }
      S.r2a[3 + 2 * u]     = e;
      S.r2a[3 + 2 * u + 1] = o;
    }
    // synth L2: 4 new r1
#pragma unroll
    for (int h = 0; h < 2; ++h) {
      float e = 0.f, o = 0.f;
#pragma unroll
      for (int m = 0; m < 4; ++m) {
        e = fmaf(LO[2 * m + 1], S.r2a[2 * u + h + m], e);
        e = fmaf(HI[2 * m + 1], S.d2a[2 * u + h + m], e);
        o = fmaf(LO[2 * m],     S.r2a[2 * u + h + m], o);
        o = fmaf(HI[2 * m],     S.d2a[2 * u + h + m], o);
      }
      S.r1a[3 + 4 * u + 2 * h]     = e;
      S.r1a[3 + 4 * u + 2 * h + 1] = o;
    }
    // synth L1 + residual + store (batch n = n0 + bk8 + 8u - 90 + {0..7})
    if (SMODE != 0) {
#pragma unroll
      for (int tau = 0; tau < 4; ++tau) {
        bool doSt;
        if (SMODE == 2)      doSt = true;
        else if (SMODE == 1) doSt = (u == 1) && (tau >= 1);
        else                 doSt = (u == 0) || (tau == 0);
        if (doSt) {
          float e = 0.f, o = 0.f;
#pragma unroll
          for (int m = 0; m < 4; ++m) {
            e = fmaf(LO[2 * m + 1], S.r1a[4 * u + tau + m], e);
            e = fmaf(HI[2 * m + 1], S.d1a[4 * u + tau + m], e);
            o = fmaf(LO[2 * m],     S.r1a[4 * u + tau + m], o);
            o = fmaf(HI[2 * m],     S.d1a[4 * u + tau + m], o);
          }
          const long ofs = bk8 + 8 * u - 90 + 2 * tau;
          orow[ofs * DCH]       = e + R[8 * u + 2 * tau];
          orow[(ofs + 1) * DCH] = o + R[8 * u + 2 * tau + 1];
        }
      }
    }
  }
  // carries: tail -> head (static renaming copies)
#pragma unroll
  for (int i = 0; i < 6; ++i)  S.xa[i]  = S.xa[i + 16];
#pragma unroll
  for (int i = 0; i < 6; ++i)  S.a1a[i] = S.a1a[i + 8];
#pragma unroll
  for (int i = 0; i < 21; ++i) S.d1a[i] = S.d1a[i + 8];
#pragma unroll
  for (int i = 0; i < 6; ++i)  S.a2a[i] = S.a2a[i + 4];
#pragma unroll
  for (int i = 0; i < 9; ++i)  S.d2a[i] = S.d2a[i + 4];
#pragma unroll
  for (int i = 0; i < 3; ++i) { S.a3a[i] = S.a3a[i + 2]; S.d3a[i] = S.d3a[i + 2]; }
#pragma unroll
  for (int i = 0; i < 3; ++i)  S.r2a[i] = S.r2a[i + 4];
#pragma unroll
  for (int i = 0; i < 3; ++i)  S.r1a[i] = S.r1a[i + 8];
}

// ---------------- edge (generic, reflecting) scalar phases ----------------

__device__ void analyze_g(const float* __restrict__ in, int Oin,
                          float* __restrict__ oa, float* __restrict__ od,
                          int cnt, int Oout, int lenout, int i2) {
  for (int p = i2; p < cnt; p += 32) {
    const int gp = refl(Oout + p, lenout);
    const int qb = 2 * gp - 6 - Oin;
    float alo = 0.f, ahi = 0.f;
#pragma unroll
    for (int k = 0; k < 8; ++k) {
      const float v = in[qb + k];
      alo = fmaf(LOF[k], v, alo);
      ahi = fmaf(HIF[k], v, ahi);
    }
    oa[p] = alo;
    od[p] = ahi;
  }
}

__device__ void synth_g(const float* __restrict__ ca,
                        const float* __restrict__ cd, int doff,
                        float* __restrict__ o, float sa, float sd, int npair,
                        int i2) {
  for (int t = i2; t < npair; t += 32) {
    float e = 0.f, ed = 0.f, oe = 0.f, od_ = 0.f;
#pragma unroll
    for (int m = 0; m < 4; ++m) {
      e   = fmaf(LO[2 * m + 1], ca[t + m], e);
      ed  = fmaf(HI[2 * m + 1], cd[t + doff + m], ed);
      oe  = fmaf(LO[2 * m],     ca[t + m], oe);
      od_ = fmaf(HI[2 * m],     cd[t + doff + m], od_);
    }
    o[2 * t]     = sa * e  + sd * ed;
    o[2 * t + 1] = sa * oe + sd * od_;
  }
}

} // namespace

__global__ __launch_bounds__(NT) void wavemix_kernel(
    const float* __restrict__ x, const float* __restrict__ wap,
    const float* __restrict__ wdet, float* __restrict__ out) {
  __shared__ float pool[G * SP];   // 31104 B (edge path only)
  const int blk = blockIdx.x;
  const int tid = threadIdx.x;

  if (blk < NINT) {
    // -------- register-streaming interior --------
    // Bijective XCD swizzle (NINT = 768 = 8*96); contiguous wgs per XCD =
    // complete (b, ch-group) rows of 32 consecutive segments -> halo
    // re-reads hit that XCD's L2.
    const int wgs    = (blk & 7) * (NINT >> 3) + (blk >> 3);
    const int si     = wgs % NSEG;          // 0..31
    const int row    = wgs / NSEG;          // 0..23
    const int wgroup = row % 3;
    const int b      = row / 3;
    const int n0     = TE + si * TS;        // 256 + si*112, covers [256,3840)
    const int d      = wgroup * 256 + tid;

    const float* __restrict__ xrow = x   + ((size_t)b * N0 + n0) * DCH + d;
    float* __restrict__       orow = out + ((size_t)b * N0 + n0) * DCH + d;
    const float wa = wap[d];
    const float w0 = wdet[d];
    const float w1 = wdet[DCH + d];
    const float w2 = wdet[2 * DCH + d];

    // Refl-free window check: x reads span [n0-48, n0+159] ⊂ [208, 3887].
    Streams S = {};
    float LA[16], LB[16], RA[16], RB[16];

    // prologue: prime the first stream batch
    issue_stream(LA, xrow, 0);
    // warm-up steps (no stores): each issues the NEXT batch, computes current
    issue_stream(LB, xrow, 16);
    compute_step<0>(S, LA, RA, orow, 0,  wa, w0, w1, w2);
    issue_stream(LA, xrow, 32);
    compute_step<0>(S, LB, RA, orow, 16, wa, w0, w1, w2);
    issue_stream(LB, xrow, 48);
    compute_step<0>(S, LA, RA, orow, 32, wa, w0, w1, w2);
    issue_stream(LA, xrow, 64);
    compute_step<0>(S, LB, RA, orow, 48, wa, w0, w1, w2);
    issue_stream(LB, xrow, 80); issue_res(RA, xrow, 80);
    compute_step<0>(S, LA, RA, orow, 64, wa, w0, w1, w2);
    // HEAD: outputs n0..n0+5
    issue_stream(LA, xrow, 96); issue_res(RB, xrow, 96);
    compute_step<1>(S, LB, RA, orow, 80, wa, w0, w1, w2);
    // FULL pairs: bk8 = 96..176 (outputs n0+6 .. n0+101)
#pragma unroll 1
    for (int m = 0; m < 3; ++m) {
      const int b0 = 96 + 32 * m;
      issue_stream(LB, xrow, b0 + 16); issue_res(RA, xrow, b0 + 16);
      compute_step<2>(S, LA, RB, orow, b0,      wa, w0, w1, w2);
      issue_stream(LA, xrow, b0 + 32); issue_res(RB, xrow, b0 + 32);
      compute_step<2>(S, LB, RA, orow, b0 + 16, wa, w0, w1, w2);
    }
    // TAIL: outputs n0+102 .. n0+111
    compute_step<3>(S, LA, RB, orow, 192, wa, w0, w1, w2);
  } else {
    // -------- edge tiles (n in [0,256) or [3840,4096)), LDS path --------
    const int e    = blk - NINT;
    const int nt   = (e & 1) ? 15 : 0;
    const int rest = e >> 1;
    const int dg   = rest % NDG;
    const int b    = rest / NDG;
    const int n0   = nt * TE;
    const int d0   = dg * G;

    // load x tile [n0-46 .. n0+305] (reflected), coalesced float4
    {
      const int q  = tid & 1;
      const int pl = tid >> 1;
      for (int p = pl; p < 352; p += 128) {
        const int g = refl(n0 - 46 + p, N0);
        const float4 v = *reinterpret_cast<const float4*>(
            x + ((size_t)b * N0 + g) * DCH + d0 + 4 * q);
        float* dst = pool + (4 * q) * SP + OX + p;
        dst[0]      = v.x;
        dst[SP]     = v.y;
        dst[2 * SP] = v.z;
        dst[3 * SP] = v.w;
      }
    }

    const int c2 = tid >> 5;
    const int i2 = tid & 31;
    float* P = pool + c2 * SP;
    const float wa = wap[d0 + c2];
    const float w2 = wdet[2 * DCH + d0 + c2];
    const float w1 = wdet[1 * DCH + d0 + c2];
    const float w0 = wdet[0 * DCH + d0 + c2];
    __syncthreads();

    analyze_g(P + OX,  n0 - 46,     P + OA1, P + OD1, 172, n0 / 2 - 20, L1v, i2);
    __syncthreads();
    analyze_g(P + OA1, n0 / 2 - 20, P + OA2, P + OD2,  82, n0 / 4 - 6,  L2v, i2);
    __syncthreads();
    analyze_g(P + OA2, n0 / 4 - 6,  P + OA3, P + OD3,  38, n0 / 8,      L3v, i2);
    __syncthreads();
    synth_g(P + OA3, P + OD3, 0, P + OA2, wa,  w2, 35, i2);  // r2 0..69
    __syncthreads();
    synth_g(P + OA2, P + OD2, 6, P + OA1, 1.f, w1, 66, i2);  // r1 0..131
    __syncthreads();
    for (int t = i2; t < 128; t += 32) {                     // final + residual
      const float* pa = P + OA1;
      const float* pd = P + OD1;
      float e2 = 0.f, ed = 0.f, oe = 0.f, od_ = 0.f;
#pragma unroll
      for (int m = 0; m < 4; ++m) {
        e2  = fmaf(LO[2 * m + 1], pa[t + m], e2);
        ed  = fmaf(HI[2 * m + 1], pd[t + 20 + m], ed);
        oe  = fmaf(LO[2 * m],     pa[t + m], oe);
        od_ = fmaf(HI[2 * m],     pd[t + 20 + m], od_);
      }
      (P + OREC)[2 * t]     = e2 + w0 * ed  + (P + OX)[2 * t + 46];
      (P + OREC)[2 * t + 1] = oe + w0 * od_ + (P + OX)[2 * t + 47];
    }
    __syncthreads();

    // coalesced store
    {
      const int c = tid & 7;
      const int j = tid >> 3;
      const float* R = pool + c * SP + OREC;
      float* orow = out + ((size_t)b * N0 + n0) * DCH + d0 + c;
      for (int pos = j; pos < TE; pos += 32)
        orow[(size_t)pos * DCH] = R[pos];
    }
  }
}

extern "C" void kernel_launch(void* const* d_in, const int* in_sizes, int n_in,
                              void* d_out, int out_size, void* d_ws, size_t ws_size,
                              hipStream_t stream) {
  const float* x  = (const float*)d_in[0];
  const float* wa = (const float*)d_in[1];
  const float* wd = (const float*)d_in[2];
  float* out      = (float*)d_out;

  const int grid = NINT + 8 * NDG * 2;   // 768 interior + 1536 edge = 2304
  wavemix_kernel<<<grid, NT, 0, stream>>>(x, wa, wd, out);
}

// Round 12
// 58.406 us; speedup vs baseline: 1.1861x; 1.1861x over previous
//
#include <hip/hip_runtime.h>

// WaveletMixing: out = x + IDWT3(scale(DWT3(x))) along N per (b,d) channel.
// x: (B=8, N=4096, D=768) f32.
// Interior (n in [256,3840)): register-streaming dataflow, 128 samples per
//   thread (28 segments x 3 ch-groups x 8 batch = 672 blocks).
//   Per superstep: 16 stream loads feed the analysis ring; the residual x is
//   NOT re-loaded from global -- a 36-float register delay ring (RR) carries
//   each x value from its stream load (~42 samples early) to its output.
//   Saves ~96 MB of issued global reads vs round 8.
// Edge tiles (n<256, n>=3840): round-5 generic LDS path (proven), same
//   dispatch, after the interior blocks.

namespace {

constexpr int NT  = 256;
constexpr int N0  = 4096;
constexpr int DCH = 768;
constexpr int TS  = 128;             // interior samples per thread
constexpr int TE  = 256;             // edge tile size
constexpr int G   = 8;               // edge path: channels per block
constexpr int NDG = DCH / G;         // 96
constexpr int L1v = 2051, L2v = 1029, L3v = 518;

constexpr int NSEG = (N0 - 2 * TE) / TS;  // 28 interior segments
constexpr int NINT = 8 * 3 * NSEG;        // 672 interior blocks

// Edge LDS pool (round-5 layout, proven)
constexpr int SP = 972;
constexpr int OX = 0, OA1 = 356, OD1 = 536, OA2 = 716, OD2 = 804,
              OA3 = 892, OD3 = 932, OREC = 716;

// db4 analysis filters ascending (pywt); HI[k] = (-1)^(k+1)*LO[7-k].
__device__ constexpr float LO[8] = {
  -0.010597401784997278f,  0.032883011666982945f,  0.030841381835986965f,
  -0.18703481171888114f,  -0.02798376941698385f,   0.6308807679295904f,
   0.7148465705525415f,    0.23037781330885523f };
__device__ constexpr float HI[8] = {
  -0.23037781330885523f,   0.7148465705525415f,   -0.6308807679295904f,
  -0.02798376941698385f,   0.18703481171888114f,   0.030841381835986965f,
  -0.032883011666982945f, -0.010597401784997278f };
// Address-ascending copies: F[7-k].
__device__ constexpr float LOF[8] = {
   0.23037781330885523f,   0.7148465705525415f,    0.6308807679295904f,
  -0.02798376941698385f,  -0.18703481171888114f,   0.030841381835986965f,
   0.032883011666982945f, -0.010597401784997278f };
__device__ constexpr float HIF[8] = {
  -0.010597401784997278f, -0.032883011666982945f,  0.030841381835986965f,
   0.18703481171888114f,  -0.02798376941698385f,  -0.6308807679295904f,
   0.7148465705525415f,   -0.23037781330885523f };

__device__ __forceinline__ int refl(int g, int n) {
  g = (g < 0) ? (-g - 1) : g;
  return (g >= n) ? (2 * n - 1 - g) : g;
}

// ---------------- streaming interior ----------------
// Array origins (abs x/coeff index of element 0 at superstep base bk8):
//  xa:  bk8 - 54 (rel n0)    a1a: bk8/2 - 30 (rel n0/2)  d1a: bk8/2 - 45
//  a2a: bk8/4 - 18           d2a: bk8/4 - 21
//  a3a/d3a: bk8/8 - 9        r2a: bk8/4 - 21             r1a: bk8/2 - 45
//  RR (residual delay ring): bk8 - 90, 36 deep.
struct Streams {
  float xa[22];
  float a1a[14], d1a[29];
  float a2a[10], d2a[13];
  float a3a[5],  d3a[5];
  float r2a[7],  r1a[11];
};

// SMODE: 0 = no stores, 1 = HEAD (store u=1, tau>=1), 2 = FULL, 3 = TAIL
// (store u=0 all + u=1 tau=0).
template <int SMODE>
__device__ __forceinline__ void superstep(Streams& S, float (&RR)[36],
                                          const float* __restrict__ xrow,
                                          float* __restrict__ orow, int bk8,
                                          float wa, float w0, float w1,
                                          float w2) {
  // 16 stream loads (x offsets bk8-48 .. bk8-33 rel n0)
#pragma unroll
  for (int i = 0; i < 16; ++i)
    S.xa[6 + i] = xrow[(long)(bk8 - 48 + i) * DCH];

#pragma unroll
  for (int u = 0; u < 2; ++u) {
    // L1 analysis: 4 new a1/d1
#pragma unroll
    for (int j = 0; j < 4; ++j) {
      float slo = 0.f, shi = 0.f;
#pragma unroll
      for (int k = 0; k < 8; ++k) {
        const float v = S.xa[8 * u + 2 * j + k];
        slo = fmaf(LOF[k], v, slo);
        shi = fmaf(HIF[k], v, shi);
      }
      S.a1a[6 + 4 * u + j]  = slo;
      S.d1a[21 + 4 * u + j] = w0 * shi;
    }
    // L2 analysis: 2 new a2/d2
#pragma unroll
    for (int i = 0; i < 2; ++i) {
      float slo = 0.f, shi = 0.f;
#pragma unroll
      for (int k = 0; k < 8; ++k) {
        const float v = S.a1a[4 * u + 2 * i + k];
        slo = fmaf(LOF[k], v, slo);
        shi = fmaf(HIF[k], v, shi);
      }
      S.a2a[6 + 2 * u + i] = slo;
      S.d2a[9 + 2 * u + i] = w1 * shi;
    }
    // L3 analysis: 1 new a3/d3 (wa/w2 folded at production)
    {
      float slo = 0.f, shi = 0.f;
#pragma unroll
      for (int k = 0; k < 8; ++k) {
        const float v = S.a2a[2 * u + k];
        slo = fmaf(LOF[k], v, slo);
        shi = fmaf(HIF[k], v, shi);
      }
      S.a3a[3 + u] = wa * slo;
      S.d3a[3 + u] = w2 * shi;
    }
    // synth L3: 2 new r2 (even output = odd taps, odd output = even taps)
    {
      float e = 0.f, o = 0.f;
#pragma unroll
      for (int m = 0; m < 4; ++m) {
        e = fmaf(LO[2 * m + 1], S.a3a[u + m], e);
        e = fmaf(HI[2 * m + 1], S.d3a[u + m], e);
        o = fmaf(LO[2 * m],     S.a3a[u + m], o);
        o = fmaf(HI[2 * m],     S.d3a[u + m], o);
      }
      S.r2a[3 + 2 * u]     = e;
      S.r2a[3 + 2 * u + 1] = o;
    }
    // synth L2: 4 new r1
#pragma unroll
    for (int h = 0; h < 2; ++h) {
      float e = 0.f, o = 0.f;
#pragma unroll
      for (int m = 0; m < 4; ++m) {
        e = fmaf(LO[2 * m + 1], S.r2a[2 * u + h + m], e);
        e = fmaf(HI[2 * m + 1], S.d2a[2 * u + h + m], e);
        o = fmaf(LO[2 * m],     S.r2a[2 * u + h + m], o);
        o = fmaf(HI[2 * m],     S.d2a[2 * u + h + m], o);
      }
      S.r1a[3 + 4 * u + 2 * h]     = e;
      S.r1a[3 + 4 * u + 2 * h + 1] = o;
    }
    // synth L1 + residual (from ring) + store
    // batch n (rel n0) = bk8 + 8u - 90 + {0..7}; RR index = 8u + 2tau (+1)
    if (SMODE != 0) {
#pragma unroll
      for (int tau = 0; tau < 4; ++tau) {
        bool doSt;
        if (SMODE == 2)      doSt = true;
        else if (SMODE == 1) doSt = (u == 1) && (tau >= 1);
        else                 doSt = (u == 0) || (tau == 0);
        if (doSt) {
          float e = 0.f, o = 0.f;
#pragma unroll
          for (int m = 0; m < 4; ++m) {
            e = fmaf(LO[2 * m + 1], S.r1a[4 * u + tau + m], e);
            e = fmaf(HI[2 * m + 1], S.d1a[4 * u + tau + m], e);
            o = fmaf(LO[2 * m],     S.r1a[4 * u + tau + m], o);
            o = fmaf(HI[2 * m],     S.d1a[4 * u + tau + m], o);
          }
          const long ofs = bk8 + 8 * u - 90 + 2 * tau;
          orow[ofs * DCH]       = e + RR[8 * u + 2 * tau];
          orow[(ofs + 1) * DCH] = o + RR[8 * u + 2 * tau + 1];
        }
      }
    }
  }
  // residual ring advance (BEFORE xa carries; uses old xa[0..15]):
  // RR_new[i] = x[(bk8+16)-90+i]
#pragma unroll
  for (int i = 0; i < 20; ++i) RR[i] = RR[i + 16];
#pragma unroll
  for (int i = 0; i < 16; ++i) RR[20 + i] = S.xa[i];
  // carries: tail -> head (static renaming copies)
#pragma unroll
  for (int i = 0; i < 6; ++i)  S.xa[i]  = S.xa[i + 16];
#pragma unroll
  for (int i = 0; i < 6; ++i)  S.a1a[i] = S.a1a[i + 8];
#pragma unroll
  for (int i = 0; i < 21; ++i) S.d1a[i] = S.d1a[i + 8];
#pragma unroll
  for (int i = 0; i < 6; ++i)  S.a2a[i] = S.a2a[i + 4];
#pragma unroll
  for (int i = 0; i < 9; ++i)  S.d2a[i] = S.d2a[i + 4];
#pragma unroll
  for (int i = 0; i < 3; ++i) { S.a3a[i] = S.a3a[i + 2]; S.d3a[i] = S.d3a[i + 2]; }
#pragma unroll
  for (int i = 0; i < 3; ++i)  S.r2a[i] = S.r2a[i + 4];
#pragma unroll
  for (int i = 0; i < 3; ++i)  S.r1a[i] = S.r1a[i + 8];
}

// ---------------- edge (generic, reflecting) scalar phases ----------------

__device__ void analyze_g(const float* __restrict__ in, int Oin,
                          float* __restrict__ oa, float* __restrict__ od,
                          int cnt, int Oout, int lenout, int i2) {
  for (int p = i2; p < cnt; p += 32) {
    const int gp = refl(Oout + p, lenout);
    const int qb = 2 * gp - 6 - Oin;
    float alo = 0.f, ahi = 0.f;
#pragma unroll
    for (int k = 0; k < 8; ++k) {
      const float v = in[qb + k];
      alo = fmaf(LOF[k], v, alo);
      ahi = fmaf(HIF[k], v, ahi);
    }
    oa[p] = alo;
    od[p] = ahi;
  }
}

__device__ void synth_g(const float* __restrict__ ca,
                        const float* __restrict__ cd, int doff,
                        float* __restrict__ o, float sa, float sd, int npair,
                        int i2) {
  for (int t = i2; t < npair; t += 32) {
    float e = 0.f, ed = 0.f, oe = 0.f, od_ = 0.f;
#pragma unroll
    for (int m = 0; m < 4; ++m) {
      e   = fmaf(LO[2 * m + 1], ca[t + m], e);
      ed  = fmaf(HI[2 * m + 1], cd[t + doff + m], ed);
      oe  = fmaf(LO[2 * m],     ca[t + m], oe);
      od_ = fmaf(HI[2 * m],     cd[t + doff + m], od_);
    }
    o[2 * t]     = sa * e  + sd * ed;
    o[2 * t + 1] = sa * oe + sd * od_;
  }
}

} // namespace

__global__ __launch_bounds__(NT) void wavemix_kernel(
    const float* __restrict__ x, const float* __restrict__ wap,
    const float* __restrict__ wdet, float* __restrict__ out) {
  __shared__ float pool[G * SP];   // 31104 B (edge path only)
  const int blk = blockIdx.x;
  const int tid = threadIdx.x;

  if (blk < NINT) {
    // -------- register-streaming interior --------
    // Bijective XCD swizzle (NINT = 672 = 8*84); contiguous wgs per XCD =
    // complete (b, ch-group) rows of 28 consecutive segments -> halo
    // re-reads hit that XCD's L2.
    const int wgs    = (blk & 7) * (NINT >> 3) + (blk >> 3);
    const int si     = wgs % NSEG;          // 0..27
    const int row    = wgs / NSEG;          // 0..23
    const int wgroup = row % 3;
    const int b      = row / 3;
    const int n0     = (si + 2) * TS;       // 256 + si*128, covers [256,3840)
    const int d      = wgroup * 256 + tid;

    const float* __restrict__ xrow = x   + ((size_t)b * N0 + n0) * DCH + d;
    float* __restrict__       orow = out + ((size_t)b * N0 + n0) * DCH + d;
    const float wa = wap[d];
    const float w0 = wdet[d];
    const float w1 = wdet[DCH + d];
    const float w2 = wdet[2 * DCH + d];

    // Refl-free window: x reads span [n0-48, n0+175] ⊂ [208, 3887].
    Streams S = {};
    float RR[36];
#pragma unroll
    for (int i = 0; i < 36; ++i) RR[i] = 0.f;

    int bk8 = 0;
    // warm-up: bk8 = 0..64 (no stores; ring primes itself from the stream)
#pragma unroll 1
    for (int m = 0; m < 5; ++m) {
      superstep<0>(S, RR, xrow, orow, bk8, wa, w0, w1, w2);
      bk8 += 16;
    }
    // HEAD: outputs n0..n0+5
    superstep<1>(S, RR, xrow, orow, bk8, wa, w0, w1, w2);
    bk8 += 16;
    // FULL: outputs n0+6 .. n0+117
#pragma unroll 1
    for (int m = 0; m < 7; ++m) {
      superstep<2>(S, RR, xrow, orow, bk8, wa, w0, w1, w2);
      bk8 += 16;
    }
    // TAIL: outputs n0+118 .. n0+127
    superstep<3>(S, RR, xrow, orow, bk8, wa, w0, w1, w2);
  } else {
    // -------- edge tiles (n in [0,256) or [3840,4096)), LDS path --------
    const int e    = blk - NINT;
    const int nt   = (e & 1) ? 15 : 0;
    const int rest = e >> 1;
    const int dg   = rest % NDG;
    const int b    = rest / NDG;
    const int n0   = nt * TE;
    const int d0   = dg * G;

    // load x tile [n0-46 .. n0+305] (reflected), coalesced float4
    {
      const int q  = tid & 1;
      const int pl = tid >> 1;
      for (int p = pl; p < 352; p += 128) {
        const int g = refl(n0 - 46 + p, N0);
        const float4 v = *reinterpret_cast<const float4*>(
            x + ((size_t)b * N0 + g) * DCH + d0 + 4 * q);
        float* dst = pool + (4 * q) * SP + OX + p;
        dst[0]      = v.x;
        dst[SP]     = v.y;
        dst[2 * SP] = v.z;
        dst[3 * SP] = v.w;
      }
    }

    const int c2 = tid >> 5;
    const int i2 = tid & 31;
    float* P = pool + c2 * SP;
    const float wa = wap[d0 + c2];
    const float w2 = wdet[2 * DCH + d0 + c2];
    const float w1 = wdet[1 * DCH + d0 + c2];
    const float w0 = wdet[0 * DCH + d0 + c2];
    __syncthreads();

    analyze_g(P + OX,  n0 - 46,     P + OA1, P + OD1, 172, n0 / 2 - 20, L1v, i2);
    __syncthreads();
    analyze_g(P + OA1, n0 / 2 - 20, P + OA2, P + OD2,  82, n0 / 4 - 6,  L2v, i2);
    __syncthreads();
    analyze_g(P + OA2, n0 / 4 - 6,  P + OA3, P + OD3,  38, n0 / 8,      L3v, i2);
    __syncthreads();
    synth_g(P + OA3, P + OD3, 0, P + OA2, wa,  w2, 35, i2);  // r2 0..69
    __syncthreads();
    synth_g(P + OA2, P + OD2, 6, P + OA1, 1.f, w1, 66, i2);  // r1 0..131
    __syncthreads();
    for (int t = i2; t < 128; t += 32) {                     // final + residual
      const float* pa = P + OA1;
      const float* pd = P + OD1;
      float e2 = 0.f, ed = 0.f, oe = 0.f, od_ = 0.f;
#pragma unroll
      for (int m = 0; m < 4; ++m) {
        e2  = fmaf(LO[2 * m + 1], pa[t + m], e2);
        ed  = fmaf(HI[2 * m + 1], pd[t + 20 + m], ed);
        oe  = fmaf(LO[2 * m],     pa[t + m], oe);
        od_ = fmaf(HI[2 * m],     pd[t + 20 + m], od_);
      }
      (P + OREC)[2 * t]     = e2 + w0 * ed  + (P + OX)[2 * t + 46];
      (P + OREC)[2 * t + 1] = oe + w0 * od_ + (P + OX)[2 * t + 47];
    }
    __syncthreads();

    // coalesced store
    {
      const int c = tid & 7;
      const int j = tid >> 3;
      const float* R = pool + c * SP + OREC;
      float* orow = out + ((size_t)b * N0 + n0) * DCH + d0 + c;
      for (int pos = j; pos < TE; pos += 32)
        orow[(size_t)pos * DCH] = R[pos];
    }
  }
}

extern "C" void kernel_launch(void* const* d_in, const int* in_sizes, int n_in,
                              void* d_out, int out_size, void* d_ws, size_t ws_size,
                              hipStream_t stream) {
  const float* x  = (const float*)d_in[0];
  const float* wa = (const float*)d_in[1];
  const float* wd = (const float*)d_in[2];
  float* out      = (float*)d_out;

  const int grid = NINT + 8 * NDG * 2;   // 672 interior + 1536 edge = 2208
  wavemix_kernel<<<grid, NT, 0, stream>>>(x, wa, wd, out);
}

// Round 13
// 53.623 us; speedup vs baseline: 1.2920x; 1.0892x over previous
//
#include <hip/hip_runtime.h>

// WaveletMixing: out = x + IDWT3(scale(DWT3(x))) along N per (b,d) channel.
// x: (B=8, N=4096, D=768) f32.
// Interior (n in [256,3840)): register-streaming dataflow, 256 samples per
//   thread (14 segments x 3 ch-groups x 8 batch = 336 blocks).
//   Per superstep: 16 stream loads feed the analysis ring; the residual x is
//   carried from stream-load to store in a 36-float register delay ring (RR)
//   -- no residual re-loads. TS=256 amortizes the 90-sample pipeline skew:
//   read-issue amplification 1.375x, FLOP amplification 1.35x (vs 1.75/1.7
//   at TS=128).
// Edge tiles (n<256, n>=3840): round-5 generic LDS path (proven), same
//   dispatch, after the interior blocks.

namespace {

constexpr int NT  = 256;
constexpr int N0  = 4096;
constexpr int DCH = 768;
constexpr int TS  = 256;             // interior samples per thread
constexpr int TE  = 256;             // edge tile size
constexpr int G   = 8;               // edge path: channels per block
constexpr int NDG = DCH / G;         // 96
constexpr int L1v = 2051, L2v = 1029, L3v = 518;

constexpr int NSEG = (N0 - 2 * TE) / TS;  // 14 interior segments
constexpr int NINT = 8 * 3 * NSEG;        // 336 interior blocks

// Edge LDS pool (round-5 layout, proven)
constexpr int SP = 972;
constexpr int OX = 0, OA1 = 356, OD1 = 536, OA2 = 716, OD2 = 804,
              OA3 = 892, OD3 = 932, OREC = 716;

// db4 analysis filters ascending (pywt); HI[k] = (-1)^(k+1)*LO[7-k].
__device__ constexpr float LO[8] = {
  -0.010597401784997278f,  0.032883011666982945f,  0.030841381835986965f,
  -0.18703481171888114f,  -0.02798376941698385f,   0.6308807679295904f,
   0.7148465705525415f,    0.23037781330885523f };
__device__ constexpr float HI[8] = {
  -0.23037781330885523f,   0.7148465705525415f,   -0.6308807679295904f,
  -0.02798376941698385f,   0.18703481171888114f,   0.030841381835986965f,
  -0.032883011666982945f, -0.010597401784997278f };
// Address-ascending copies: F[7-k].
__device__ constexpr float LOF[8] = {
   0.23037781330885523f,   0.7148465705525415f,    0.6308807679295904f,
  -0.02798376941698385f,  -0.18703481171888114f,   0.030841381835986965f,
   0.032883011666982945f, -0.010597401784997278f };
__device__ constexpr float HIF[8] = {
  -0.010597401784997278f, -0.032883011666982945f,  0.030841381835986965f,
   0.18703481171888114f,  -0.02798376941698385f,  -0.6308807679295904f,
   0.7148465705525415f,   -0.23037781330885523f };

__device__ __forceinline__ int refl(int g, int n) {
  g = (g < 0) ? (-g - 1) : g;
  return (g >= n) ? (2 * n - 1 - g) : g;
}

// ---------------- streaming interior ----------------
// Array origins (x/coeff index of element 0 rel n0 at superstep base bk8):
//  xa:  bk8 - 54             a1a: bk8/2 - 30             d1a: bk8/2 - 45
//  a2a: bk8/4 - 18           d2a: bk8/4 - 21
//  a3a/d3a: bk8/8 - 9        r2a: bk8/4 - 21             r1a: bk8/2 - 45
//  RR (residual delay ring): bk8 - 90, 36 deep.
struct Streams {
  float xa[22];
  float a1a[14], d1a[29];
  float a2a[10], d2a[13];
  float a3a[5],  d3a[5];
  float r2a[7],  r1a[11];
};

// SMODE: 0 = no stores, 1 = HEAD (store u=1, tau>=1), 2 = FULL, 3 = TAIL
// (store u=0 all + u=1 tau=0).
template <int SMODE>
__device__ __forceinline__ void superstep(Streams& S, float (&RR)[36],
                                          const float* __restrict__ xrow,
                                          float* __restrict__ orow, int bk8,
                                          float wa, float w0, float w1,
                                          float w2) {
  // 16 stream loads (x offsets bk8-48 .. bk8-33 rel n0)
#pragma unroll
  for (int i = 0; i < 16; ++i)
    S.xa[6 + i] = xrow[(long)(bk8 - 48 + i) * DCH];

#pragma unroll
  for (int u = 0; u < 2; ++u) {
    // L1 analysis: 4 new a1/d1
#pragma unroll
    for (int j = 0; j < 4; ++j) {
      float slo = 0.f, shi = 0.f;
#pragma unroll
      for (int k = 0; k < 8; ++k) {
        const float v = S.xa[8 * u + 2 * j + k];
        slo = fmaf(LOF[k], v, slo);
        shi = fmaf(HIF[k], v, shi);
      }
      S.a1a[6 + 4 * u + j]  = slo;
      S.d1a[21 + 4 * u + j] = w0 * shi;
    }
    // L2 analysis: 2 new a2/d2
#pragma unroll
    for (int i = 0; i < 2; ++i) {
      float slo = 0.f, shi = 0.f;
#pragma unroll
      for (int k = 0; k < 8; ++k) {
        const float v = S.a1a[4 * u + 2 * i + k];
        slo = fmaf(LOF[k], v, slo);
        shi = fmaf(HIF[k], v, shi);
      }
      S.a2a[6 + 2 * u + i] = slo;
      S.d2a[9 + 2 * u + i] = w1 * shi;
    }
    // L3 analysis: 1 new a3/d3 (wa/w2 folded at production)
    {
      float slo = 0.f, shi = 0.f;
#pragma unroll
      for (int k = 0; k < 8; ++k) {
        const float v = S.a2a[2 * u + k];
        slo = fmaf(LOF[k], v, slo);
        shi = fmaf(HIF[k], v, shi);
      }
      S.a3a[3 + u] = wa * slo;
      S.d3a[3 + u] = w2 * shi;
    }
    // synth L3: 2 new r2 (even output = odd taps, odd output = even taps)
    {
      float e = 0.f, o = 0.f;
#pragma unroll
      for (int m = 0; m < 4; ++m) {
        e = fmaf(LO[2 * m + 1], S.a3a[u + m], e);
        e = fmaf(HI[2 * m + 1], S.d3a[u + m], e);
        o = fmaf(LO[2 * m],     S.a3a[u + m], o);
        o = fmaf(HI[2 * m],     S.d3a[u + m], o);
      }
      S.r2a[3 + 2 * u]     = e;
      S.r2a[3 + 2 * u + 1] = o;
    }
    // synth L2: 4 new r1
#pragma unroll
    for (int h = 0; h < 2; ++h) {
      float e = 0.f, o = 0.f;
#pragma unroll
      for (int m = 0; m < 4; ++m) {
        e = fmaf(LO[2 * m + 1], S.r2a[2 * u + h + m], e);
        e = fmaf(HI[2 * m + 1], S.d2a[2 * u + h + m], e);
        o = fmaf(LO[2 * m],     S.r2a[2 * u + h + m], o);
        o = fmaf(HI[2 * m],     S.d2a[2 * u + h + m], o);
      }
      S.r1a[3 + 4 * u + 2 * h]     = e;
      S.r1a[3 + 4 * u + 2 * h + 1] = o;
    }
    // synth L1 + residual (from ring) + store
    // batch n (rel n0) = bk8 + 8u - 90 + {0..7}; RR index = 8u + 2tau (+1)
    if (SMODE != 0) {
#pragma unroll
      for (int tau = 0; tau < 4; ++tau) {
        bool doSt;
        if (SMODE == 2)      doSt = true;
        else if (SMODE == 1) doSt = (u == 1) && (tau >= 1);
        else                 doSt = (u == 0) || (tau == 0);
        if (doSt) {
          float e = 0.f, o = 0.f;
#pragma unroll
          for (int m = 0; m < 4; ++m) {
            e = fmaf(LO[2 * m + 1], S.r1a[4 * u + tau + m], e);
            e = fmaf(HI[2 * m + 1], S.d1a[4 * u + tau + m], e);
            o = fmaf(LO[2 * m],     S.r1a[4 * u + tau + m], o);
            o = fmaf(HI[2 * m],     S.d1a[4 * u + tau + m], o);
          }
          const long ofs = bk8 + 8 * u - 90 + 2 * tau;
          orow[ofs * DCH]       = e + RR[8 * u + 2 * tau];
          orow[(ofs + 1) * DCH] = o + RR[8 * u + 2 * tau + 1];
        }
      }
    }
  }
  // residual ring advance (BEFORE xa carries; uses old xa[0..15]):
  // RR_new[i] = x[(bk8+16)-90+i]
#pragma unroll
  for (int i = 0; i < 20; ++i) RR[i] = RR[i + 16];
#pragma unroll
  for (int i = 0; i < 16; ++i) RR[20 + i] = S.xa[i];
  // carries: tail -> head (static renaming copies)
#pragma unroll
  for (int i = 0; i < 6; ++i)  S.xa[i]  = S.xa[i + 16];
#pragma unroll
  for (int i = 0; i < 6; ++i)  S.a1a[i] = S.a1a[i + 8];
#pragma unroll
  for (int i = 0; i < 21; ++i) S.d1a[i] = S.d1a[i + 8];
#pragma unroll
  for (int i = 0; i < 6; ++i)  S.a2a[i] = S.a2a[i + 4];
#pragma unroll
  for (int i = 0; i < 9; ++i)  S.d2a[i] = S.d2a[i + 4];
#pragma unroll
  for (int i = 0; i < 3; ++i) { S.a3a[i] = S.a3a[i + 2]; S.d3a[i] = S.d3a[i + 2]; }
#pragma unroll
  for (int i = 0; i < 3; ++i)  S.r2a[i] = S.r2a[i + 4];
#pragma unroll
  for (int i = 0; i < 3; ++i)  S.r1a[i] = S.r1a[i + 8];
}

// ---------------- edge (generic, reflecting) scalar phases ----------------

__device__ void analyze_g(const float* __restrict__ in, int Oin,
                          float* __restrict__ oa, float* __restrict__ od,
                          int cnt, int Oout, int lenout, int i2) {
  for (int p = i2; p < cnt; p += 32) {
    const int gp = refl(Oout + p, lenout);
    const int qb = 2 * gp - 6 - Oin;
    float alo = 0.f, ahi = 0.f;
#pragma unroll
    for (int k = 0; k < 8; ++k) {
      const float v = in[qb + k];
      alo = fmaf(LOF[k], v, alo);
      ahi = fmaf(HIF[k], v, ahi);
    }
    oa[p] = alo;
    od[p] = ahi;
  }
}

__device__ void synth_g(const float* __restrict__ ca,
                        const float* __restrict__ cd, int doff,
                        float* __restrict__ o, float sa, float sd, int npair,
                        int i2) {
  for (int t = i2; t < npair; t += 32) {
    float e = 0.f, ed = 0.f, oe = 0.f, od_ = 0.f;
#pragma unroll
    for (int m = 0; m < 4; ++m) {
      e   = fmaf(LO[2 * m + 1], ca[t + m], e);
      ed  = fmaf(HI[2 * m + 1], cd[t + doff + m], ed);
      oe  = fmaf(LO[2 * m],     ca[t + m], oe);
      od_ = fmaf(HI[2 * m],     cd[t + doff + m], od_);
    }
    o[2 * t]     = sa * e  + sd * ed;
    o[2 * t + 1] = sa * oe + sd * od_;
  }
}

} // namespace

__global__ __launch_bounds__(NT) void wavemix_kernel(
    const float* __restrict__ x, const float* __restrict__ wap,
    const float* __restrict__ wdet, float* __restrict__ out) {
  __shared__ float pool[G * SP];   // 31104 B (edge path only)
  const int blk = blockIdx.x;
  const int tid = threadIdx.x;

  if (blk < NINT) {
    // -------- register-streaming interior --------
    // Bijective XCD swizzle (NINT = 336 = 8*42); contiguous wgs per XCD =
    // 3 complete (b, ch-group) rows of 14 consecutive segments -> halo
    // re-reads hit that XCD's L2.
    const int wgs    = (blk & 7) * (NINT >> 3) + (blk >> 3);
    const int si     = wgs % NSEG;          // 0..13
    const int row    = wgs / NSEG;          // 0..23
    const int wgroup = row % 3;
    const int b      = row / 3;
    const int n0     = (si + 1) * TS;       // 256 + si*256, covers [256,3840)
    const int d      = wgroup * 256 + tid;

    const float* __restrict__ xrow = x   + ((size_t)b * N0 + n0) * DCH + d;
    float* __restrict__       orow = out + ((size_t)b * N0 + n0) * DCH + d;
    const float wa = wap[d];
    const float w0 = wdet[d];
    const float w1 = wdet[DCH + d];
    const float w2 = wdet[2 * DCH + d];

    // Refl-free window: x reads span [n0-48, n0+303] ⊂ [208, 3887].
    Streams S = {};
    float RR[36];
#pragma unroll
    for (int i = 0; i < 36; ++i) RR[i] = 0.f;

    int bk8 = 0;
    // warm-up: bk8 = 0..64 (no stores; ring primes itself from the stream)
#pragma unroll 1
    for (int m = 0; m < 5; ++m) {
      superstep<0>(S, RR, xrow, orow, bk8, wa, w0, w1, w2);
      bk8 += 16;
    }
    // HEAD: outputs n0..n0+5
    superstep<1>(S, RR, xrow, orow, bk8, wa, w0, w1, w2);
    bk8 += 16;
    // FULL: outputs n0+6 .. n0+245
#pragma unroll 1
    for (int m = 0; m < 15; ++m) {
      superstep<2>(S, RR, xrow, orow, bk8, wa, w0, w1, w2);
      bk8 += 16;
    }
    // TAIL: outputs n0+246 .. n0+255
    superstep<3>(S, RR, xrow, orow, bk8, wa, w0, w1, w2);
  } else {
    // -------- edge tiles (n in [0,256) or [3840,4096)), LDS path --------
    const int e    = blk - NINT;
    const int nt   = (e & 1) ? 15 : 0;
    const int rest = e >> 1;
    const int dg   = rest % NDG;
    const int b    = rest / NDG;
    const int n0   = nt * TE;
    const int d0   = dg * G;

    // load x tile [n0-46 .. n0+305] (reflected), coalesced float4
    {
      const int q  = tid & 1;
      const int pl = tid >> 1;
      for (int p = pl; p < 352; p += 128) {
        const int g = refl(n0 - 46 + p, N0);
        const float4 v = *reinterpret_cast<const float4*>(
            x + ((size_t)b * N0 + g) * DCH + d0 + 4 * q);
        float* dst = pool + (4 * q) * SP + OX + p;
        dst[0]      = v.x;
        dst[SP]     = v.y;
        dst[2 * SP] = v.z;
        dst[3 * SP] = v.w;
      }
    }

    const int c2 = tid >> 5;
    const int i2 = tid & 31;
    float* P = pool + c2 * SP;
    const float wa = wap[d0 + c2];
    const float w2 = wdet[2 * DCH + d0 + c2];
    const float w1 = wdet[1 * DCH + d0 + c2];
    const float w0 = wdet[0 * DCH + d0 + c2];
    __syncthreads();

    analyze_g(P + OX,  n0 - 46,     P + OA1, P + OD1, 172, n0 / 2 - 20, L1v, i2);
    __syncthreads();
    analyze_g(P + OA1, n0 / 2 - 20, P + OA2, P + OD2,  82, n0 / 4 - 6,  L2v, i2);
    __syncthreads();
    analyze_g(P + OA2, n0 / 4 - 6,  P + OA3, P + OD3,  38, n0 / 8,      L3v, i2);
    __syncthreads();
    synth_g(P + OA3, P + OD3, 0, P + OA2, wa,  w2, 35, i2);  // r2 0..69
    __syncthreads();
    synth_g(P + OA2, P + OD2, 6, P + OA1, 1.f, w1, 66, i2);  // r1 0..131
    __syncthreads();
    for (int t = i2; t < 128; t += 32) {                     // final + residual
      const float* pa = P + OA1;
      const float* pd = P + OD1;
      float e2 = 0.f, ed = 0.f, oe = 0.f, od_ = 0.f;
#pragma unroll
      for (int m = 0; m < 4; ++m) {
        e2  = fmaf(LO[2 * m + 1], pa[t + m], e2);
        ed  = fmaf(HI[2 * m + 1], pd[t + 20 + m], ed);
        oe  = fmaf(LO[2 * m],     pa[t + m], oe);
        od_ = fmaf(HI[2 * m],     pd[t + 20 + m], od_);
      }
      (P + OREC)[2 * t]     = e2 + w0 * ed  + (P + OX)[2 * t + 46];
      (P + OREC)[2 * t + 1] = oe + w0 * od_ + (P + OX)[2 * t + 47];
    }
    __syncthreads();

    // coalesced store
    {
      const int c = tid & 7;
      const int j = tid >> 3;
      const float* R = pool + c * SP + OREC;
      float* orow = out + ((size_t)b * N0 + n0) * DCH + d0 + c;
      for (int pos = j; pos < TE; pos += 32)
        orow[(size_t)pos * DCH] = R[pos];
    }
  }
}

extern "C" void kernel_launch(void* const* d_in, const int* in_sizes, int n_in,
                              void* d_out, int out_size, void* d_ws, size_t ws_size,
                              hipStream_t stream) {
  const float* x  = (const float*)d_in[0];
  const float* wa = (const float*)d_in[1];
  const float* wd = (const float*)d_in[2];
  float* out      = (float*)d_out;

  const int grid = NINT + 8 * NDG * 2;   // 336 interior + 1536 edge = 1872
  wavemix_kernel<<<grid, NT, 0, stream>>>(x, wa, wd, out);
}